// Round 7
// baseline (46.367 us; speedup 1.0000x reference)
//
#include <hip/hip_runtime.h>
#include <hip/hip_bf16.h>

// B=2, L=S=2048, H=8, E=D=64. Dense attention.
// out[b,l,h,d] = softmax_s( (1/8) * sum_e Q[b,l,h,e]K[b,s,h,e] ) @ V[b,s,h,d]

#define LOG2E 1.44269504088896340736f
#define SCL2 0.18033688011112042f   // 0.125 * LOG2E (scale folded into exp2 argument)

#if __has_builtin(__builtin_amdgcn_exp2f)
#define EXP2(x) __builtin_amdgcn_exp2f(x)
#else
#define EXP2(x) exp2f(x)
#endif

typedef __attribute__((ext_vector_type(8))) short bf16x8;   // 8 bf16 = 4 VGPRs
typedef __attribute__((ext_vector_type(4))) float f32x4;
typedef __attribute__((ext_vector_type(16))) float f32x16;

static constexpr int Bc = 2, Lc = 2048, Sc = 2048, Hc = 8, Ec = 64, Dc = 64;
static constexpr int BH = Bc * Hc;                 // 16
static constexpr int ELEMS = Bc * Lc * Hc * Ec;    // 2097152 per tensor

static __device__ __forceinline__ unsigned short bfb(float x) {
  union { __hip_bfloat16 h; unsigned short u; } c;
  c.h = __float2bfloat16(x);
  return c.u;
}
static __device__ __forceinline__ unsigned pkbf(float a, float b) {
  union { __hip_bfloat162 h; unsigned u; } c;
  c.h = __float22bfloat162_rn(make_float2(a, b));  // -> v_cvt_pk_bf16_f32
  return c.u;
}
static __device__ __forceinline__ bf16x8 pack4(unsigned w0, unsigned w1,
                                               unsigned w2, unsigned w3) {
  union { unsigned u[4]; bf16x8 v; } c;
  c.u[0] = w0; c.u[1] = w1; c.u[2] = w2; c.u[3] = w3;
  return c.v;
}

// permlane32_swap: o0 = [a.lo | b.lo], o1 = [a.hi | b.hi] (lane<32 / lane>=32 exchange)
static __device__ __forceinline__ void plswap(unsigned a, unsigned b,
                                              unsigned& o0, unsigned& o1, int hi) {
#if __has_builtin(__builtin_amdgcn_permlane32_swap)
  auto r = __builtin_amdgcn_permlane32_swap(a, b, false, false);
  o0 = r[0];
  o1 = r[1];
#else
  unsigned ax = (unsigned)__shfl_xor((int)a, 32);
  unsigned bx = (unsigned)__shfl_xor((int)b, 32);
  o0 = hi ? bx : a;
  o1 = hi ? b : ax;
#endif
}
static __device__ __forceinline__ float cross_half_max(float x, int hi) {
  unsigned ua, ub;
  plswap(__float_as_uint(x), __float_as_uint(x), ua, ub, hi);
  return fmaxf(__uint_as_float(ua), __uint_as_float(ub));
}
static __device__ __forceinline__ float cross_half_sum(float x, int hi) {
  unsigned ua, ub;
  plswap(__float_as_uint(x), __float_as_uint(x), ua, ub, hi);
  return __uint_as_float(ua) + __uint_as_float(ub);
}

// async global -> LDS DMA, 16B per lane. LDS dest = uniform base + lane*16 (HW).
static __device__ __forceinline__ void gld16(const __hip_bfloat16* g, __hip_bfloat16* l) {
  __builtin_amdgcn_global_load_lds(
      (const __attribute__((address_space(1))) void*)g,
      (__attribute__((address_space(3))) void*)l, 16, 0, 0);
}

// ---- Fused prepass: K -> frag-major bf16, V -> transposed frag-major bf16 ----
__global__ __launch_bounds__(256) void prep_kv_kernel(const float* __restrict__ K,
                                                      const float* __restrict__ V,
                                                      __hip_bfloat16* __restrict__ Kc,
                                                      __hip_bfloat16* __restrict__ Vt) {
  __shared__ __hip_bfloat16 tile[4][64][68];   // per-wave V transpose tile (padded)
  if (blockIdx.x < 1024) {
    // ---- K section: pointwise relayout, 8 elems/thread ----
    int t = blockIdx.x * 256 + threadIdx.x;    // ELEMS/8 threads
    int f = t * 8;                             // ((b*S + s)*H + h)*64 + e
    int e = f & 63;
    int h = (f >> 6) & 7;
    int s = (f >> 9) & 2047;
    int b = f >> 20;
    float4 v0 = *reinterpret_cast<const float4*>(K + f);
    float4 v1 = *reinterpret_cast<const float4*>(K + f + 4);
    int es = e >> 4, hi = (e >> 3) & 1;
    int kb = s >> 5, qi = s & 31;
    int o = ((b << 3) + h) * (Sc * 64) + kb * 2048 + es * 512 + hi * 256 + qi * 8;
    union { ushort u[8]; uint4 q; } pk;
    pk.u[0] = bfb(v0.x); pk.u[1] = bfb(v0.y); pk.u[2] = bfb(v0.z); pk.u[3] = bfb(v0.w);
    pk.u[4] = bfb(v1.x); pk.u[5] = bfb(v1.y); pk.u[6] = bfb(v1.z); pk.u[7] = bfb(v1.w);
    *reinterpret_cast<uint4*>(Kc + o) = pk.q;
  } else {
    // ---- V section: 4 waves, each transposes one 64-key tile of one head ----
    const int w = threadIdx.x >> 6;
    const int lane = threadIdx.x & 63;
    const int task = (blockIdx.x - 1024) * 4 + w;  // 512 tasks = 32 s-tiles x 16 heads
    const int st = task & 31;
    const int bh = task >> 5;
    const int s0 = st * 64;
    const int b = bh >> 3, h = bh & 7;
#pragma unroll 4
    for (int j = 0; j < 64; ++j) {
      float v = V[((b * Sc + s0 + j) * Hc + h) * 64 + lane];  // coalesced 256B rows
      tile[w][j][lane] = __float2bfloat16(v);
    }
    __syncthreads();
    const int qi = lane & 31, hi = lane >> 5;
    __hip_bfloat16* Vb = Vt + bh * (Sc * 64);
#pragma unroll
    for (int kb2 = 0; kb2 < 2; ++kb2)
#pragma unroll
      for (int d0 = 0; d0 < 2; ++d0)
#pragma unroll
        for (int ks = 0; ks < 2; ++ks) {
          union { ushort u[8]; uint4 q; } pk;
#pragma unroll
          for (int j = 0; j < 8; ++j) {
            union { __hip_bfloat16 h; ushort u; } c;
            c.h = tile[w][kb2 * 32 + ks * 16 + hi * 8 + j][d0 * 32 + qi];
            pk.u[j] = c.u;
          }
          int o = ((s0 >> 5) + kb2) * 2048 + d0 * 1024 + ks * 512 + lane * 8;
          *reinterpret_cast<uint4*>(Vb + o) = pk.q;   // coalesced 1KB
        }
  }
}

// online-softmax for one q-group. l is a PER-HALF-LANE partial (combined after loop);
// max permlane only on the (rare) rescale path.
static __device__ __forceinline__ void sm_group(f32x16& sc, float& m, float& l,
                                                f32x16& oA, f32x16& oB, int hi,
                                                bf16x8& pb0, bf16x8& pb1) {
  float x0 = fmaxf(fmaxf(sc[0], sc[1]), fmaxf(sc[2], sc[3]));
  float x1 = fmaxf(fmaxf(sc[4], sc[5]), fmaxf(sc[6], sc[7]));
  float x2 = fmaxf(fmaxf(sc[8], sc[9]), fmaxf(sc[10], sc[11]));
  float x3 = fmaxf(fmaxf(sc[12], sc[13]), fmaxf(sc[14], sc[15]));
  float mx = fmaxf(fmaxf(x0, x1), fmaxf(x2, x3));   // lane-local 16-key max

  // defer-max (T13): 64 raw units = 8 nats (P bounded by e^8). Cross-half max only here.
  if (__any(mx > m + 64.0f)) {
    float mrow = cross_half_max(mx, hi);
    float mnew = fmaxf(m, mrow);
    float corr = EXP2((m - mnew) * SCL2);
    l *= corr;
#pragma unroll
    for (int r = 0; r < 16; ++r) { oA[r] *= corr; oB[r] *= corr; }
    m = mnew;
  }
  float mL = m * SCL2;
#pragma unroll
  for (int r = 0; r < 16; ++r) sc[r] = EXP2(sc[r] * SCL2 - mL);  // fma + exp

  float r0 = (sc[0] + sc[1]) + (sc[2] + sc[3]);
  float r1 = (sc[4] + sc[5]) + (sc[6] + sc[7]);
  float r2 = (sc[8] + sc[9]) + (sc[10] + sc[11]);
  float r3 = (sc[12] + sc[13]) + (sc[14] + sc[15]);
  l += (r0 + r1) + (r2 + r3);                       // per-half partial, no permlane

  // P^T B-frags via cvt_pk + permlane32_swap (T12)
  unsigned c0, c1, c2, c3, y0, y1, y2, y3;
  c0 = pkbf(sc[0], sc[1]);  c1 = pkbf(sc[4], sc[5]);
  c2 = pkbf(sc[2], sc[3]);  c3 = pkbf(sc[6], sc[7]);
  plswap(c0, c1, y0, y2, hi);
  plswap(c2, c3, y1, y3, hi);
  pb0 = pack4(y0, y1, y2, y3);
  c0 = pkbf(sc[8], sc[9]);   c1 = pkbf(sc[12], sc[13]);
  c2 = pkbf(sc[10], sc[11]); c3 = pkbf(sc[14], sc[15]);
  plswap(c0, c1, y0, y2, hi);
  plswap(c2, c3, y1, y3, hi);
  pb1 = pack4(y0, y1, y2, y3);
}

// ---- Attention: 32x32 swapped MFMA, 64 q-rows/wave, wave-private LDS DMA pipeline ----
// Grid: 512 blocks = 8 XCD x 2 heads x 32 q-tiles(64 rows). K/V 1MB/XCD -> L2-resident.
// Per wave: private 2 x 8KB LDS double-buffer fed by global_load_lds (zero VGPR cost);
// vmcnt(0) at iter top waits for the stage issued one full compute phase earlier.
// No cross-wave barriers in the loop (wave-private buffers) -> no lockstep.
__global__ __launch_bounds__(256, 2) void attn_kernel(const float* __restrict__ Qf,
                                                      const __hip_bfloat16* __restrict__ Kc,
                                                      const __hip_bfloat16* __restrict__ Vt,
                                                      float* __restrict__ Out) {
  // kv staging (loop) and obuf (epilogue) are temporally disjoint -> union them.
  union SMem {
    __hip_bfloat16 kv[4][2][4096];   // [wave][buf][K 0..2047 | V 2048..4095] = 64KB
    float obuf[4][2][16][64];        // [wave][d0][reg][lane] = 32KB
  };
  __shared__ SMem sm;
  __shared__ float mlb[2][4][2][32];  // [group][wave][{m,l}][q]  (outside union)

  const int lid = blockIdx.x;         // 512 = 8 xcd * 2 heads * 32 qtiles
  const int xcd = lid & 7;
  const int i = lid >> 3;             // 0..63
  const int bh = (xcd << 1) | (i >> 5);
  const int q0 = (i & 31) << 6;       // 64 q rows per block
  const int w = threadIdx.x >> 6;
  const int lane = threadIdx.x & 63;
  const int qi = lane & 31;
  const int hi = lane >> 5;
  const int b = bh >> 3, h = bh & 7;

  const __hip_bfloat16* Kh = Kc + bh * (Sc * 64);   // frag-major
  const __hip_bfloat16* Vh = Vt + bh * (Sc * 64);   // frag-major

  auto stage = [&](int t, int c) {    // DMA tile t (keys w*32+t*128 ..+32) into buf c
    const int tb = (w + 4 * t) * 2048;  // (s>>5)*2048
    const __hip_bfloat16* Ks = Kh + tb + lane * 8;
    const __hip_bfloat16* Vs = Vh + tb + lane * 8;
#pragma unroll
    for (int f = 0; f < 4; ++f) gld16(Ks + f * 512, &sm.kv[w][c][f * 512]);
#pragma unroll
    for (int f = 0; f < 4; ++f) gld16(Vs + f * 512, &sm.kv[w][c][2048 + f * 512]);
  };

  // Q frags straight from f32 input (scale folded into exp2 arg)
  bf16x8 qf[2][4];
#pragma unroll
  for (int g = 0; g < 2; ++g) {
    const float* qrow = Qf + ((b * Lc + q0 + g * 32 + qi) * Hc + h) * 64 + hi * 8;
#pragma unroll
    for (int es = 0; es < 4; ++es) {
      float4 a = *reinterpret_cast<const float4*>(qrow + es * 16);
      float4 c = *reinterpret_cast<const float4*>(qrow + es * 16 + 4);
      qf[g][es] = pack4(pkbf(a.x, a.y), pkbf(a.z, a.w), pkbf(c.x, c.y), pkbf(c.z, c.w));
    }
  }

  f32x16 zero;
#pragma unroll
  for (int r = 0; r < 16; ++r) zero[r] = 0.f;      // loop-invariant MFMA C-input

  f32x16 oa0 = zero, ob0 = zero, oa1 = zero, ob1 = zero;
  float m0 = -1.0e30f, l0 = 0.f, m1 = -1.0e30f, l1 = 0.f;

  stage(0, 0);                       // prologue: tile 0 in flight
  int cur = 0;

  for (int t = 0; t < 16; ++t) {
    // wait for buf[cur]'s DMA (issued one compute phase ago); pin nothing above it
    asm volatile("s_waitcnt vmcnt(0)" ::: "memory");
    __builtin_amdgcn_sched_barrier(0);

    // read this tile's frags back (each lane reads its own 16B slot; contiguous)
    const __hip_bfloat16* kb = &sm.kv[w][cur][lane * 8];
    bf16x8 k0 = *reinterpret_cast<const bf16x8*>(kb + 0 * 512);
    bf16x8 k1 = *reinterpret_cast<const bf16x8*>(kb + 1 * 512);
    bf16x8 k2 = *reinterpret_cast<const bf16x8*>(kb + 2 * 512);
    bf16x8 k3 = *reinterpret_cast<const bf16x8*>(kb + 3 * 512);
    bf16x8 v0 = *reinterpret_cast<const bf16x8*>(kb + 4 * 512);
    bf16x8 v1 = *reinterpret_cast<const bf16x8*>(kb + 5 * 512);
    bf16x8 v2 = *reinterpret_cast<const bf16x8*>(kb + 6 * 512);
    bf16x8 v3 = *reinterpret_cast<const bf16x8*>(kb + 7 * 512);

    if (t + 1 < 16) stage(t + 1, cur ^ 1);   // next tile's DMA rides under compute

    f32x16 sc0, sc1;
    __builtin_amdgcn_s_setprio(1);
    sc0 = __builtin_amdgcn_mfma_f32_32x32x16_bf16(k0, qf[0][0], zero, 0, 0, 0);
    sc0 = __builtin_amdgcn_mfma_f32_32x32x16_bf16(k1, qf[0][1], sc0, 0, 0, 0);
    sc0 = __builtin_amdgcn_mfma_f32_32x32x16_bf16(k2, qf[0][2], sc0, 0, 0, 0);
    sc0 = __builtin_amdgcn_mfma_f32_32x32x16_bf16(k3, qf[0][3], sc0, 0, 0, 0);
    sc1 = __builtin_amdgcn_mfma_f32_32x32x16_bf16(k0, qf[1][0], zero, 0, 0, 0);
    sc1 = __builtin_amdgcn_mfma_f32_32x32x16_bf16(k1, qf[1][1], sc1, 0, 0, 0);
    sc1 = __builtin_amdgcn_mfma_f32_32x32x16_bf16(k2, qf[1][2], sc1, 0, 0, 0);
    sc1 = __builtin_amdgcn_mfma_f32_32x32x16_bf16(k3, qf[1][3], sc1, 0, 0, 0);
    __builtin_amdgcn_s_setprio(0);

    bf16x8 pb0, pb1;
    sm_group(sc0, m0, l0, oa0, ob0, hi, pb0, pb1);
    __builtin_amdgcn_s_setprio(1);
    oa0 = __builtin_amdgcn_mfma_f32_32x32x16_bf16(v0, pb0, oa0, 0, 0, 0);
    oa0 = __builtin_amdgcn_mfma_f32_32x32x16_bf16(v1, pb1, oa0, 0, 0, 0);
    ob0 = __builtin_amdgcn_mfma_f32_32x32x16_bf16(v2, pb0, ob0, 0, 0, 0);
    ob0 = __builtin_amdgcn_mfma_f32_32x32x16_bf16(v3, pb1, ob0, 0, 0, 0);
    __builtin_amdgcn_s_setprio(0);

    sm_group(sc1, m1, l1, oa1, ob1, hi, pb0, pb1);
    __builtin_amdgcn_s_setprio(1);
    oa1 = __builtin_amdgcn_mfma_f32_32x32x16_bf16(v0, pb0, oa1, 0, 0, 0);
    oa1 = __builtin_amdgcn_mfma_f32_32x32x16_bf16(v1, pb1, oa1, 0, 0, 0);
    ob1 = __builtin_amdgcn_mfma_f32_32x32x16_bf16(v2, pb0, ob1, 0, 0, 0);
    ob1 = __builtin_amdgcn_mfma_f32_32x32x16_bf16(v3, pb1, ob1, 0, 0, 0);
    __builtin_amdgcn_s_setprio(0);

    cur ^= 1;
  }

  // combine per-half l partials -> full row sums
  l0 = cross_half_sum(l0, hi);
  l1 = cross_half_sum(l1, hi);

  // ---- cross-wave combine (4 S-split partials), per q-group through shared obuf ----
  if (hi == 0) {
    mlb[0][w][0][qi] = m0; mlb[0][w][1][qi] = l0;
    mlb[1][w][0][qi] = m1; mlb[1][w][1][qi] = l1;
  }
  __syncthreads();   // also fences: all waves done with their kv region before obuf reuse
  float myf[2], inv[2];
#pragma unroll
  for (int g = 0; g < 2; ++g) {
    float mm = fmaxf(fmaxf(mlb[g][0][0][qi], mlb[g][1][0][qi]),
                     fmaxf(mlb[g][2][0][qi], mlb[g][3][0][qi]));
    float Lt = 0.f;
#pragma unroll
    for (int sw = 0; sw < 4; ++sw)
      Lt += EXP2((mlb[g][sw][0][qi] - mm) * SCL2) * mlb[g][sw][1][qi];
    float mreg = g ? m1 : m0;
    myf[g] = EXP2((mreg - mm) * SCL2);
    inv[g] = 1.0f / Lt;
  }
  const int d0 = w >> 1, rr = (w & 1) * 8;
#pragma unroll
  for (int g = 0; g < 2; ++g) {
    if (g) __syncthreads();
    const f32x16& A = g ? oa1 : oa0;
    const f32x16& Bv = g ? ob1 : ob0;
#pragma unroll
    for (int r = 0; r < 16; ++r) {
      sm.obuf[w][0][r][lane] = A[r] * myf[g];
      sm.obuf[w][1][r][lane] = Bv[r] * myf[g];
    }
    __syncthreads();
    float* orow = Out + ((b * Lc + q0 + g * 32 + qi) * Hc + h) * Dc;
#pragma unroll
    for (int t = 0; t < 2; ++t) {
      f32x4 acc;
#pragma unroll
      for (int j = 0; j < 4; ++j) {
        const int r = rr + 4 * t + j;
        acc[j] = (sm.obuf[0][d0][r][lane] + sm.obuf[1][d0][r][lane] +
                  sm.obuf[2][d0][r][lane] + sm.obuf[3][d0][r][lane]) * inv[g];
      }
      const int dbase = d0 * 32 + ((rr + 4 * t) >> 2) * 8 + hi * 4;
      *reinterpret_cast<f32x4*>(orow + dbase) = acc;
    }
  }
}

extern "C" void kernel_launch(void* const* d_in, const int* in_sizes, int n_in,
                              void* d_out, int out_size, void* d_ws, size_t ws_size,
                              hipStream_t stream) {
  const float* Q = (const float*)d_in[0];
  const float* K = (const float*)d_in[1];
  const float* V = (const float*)d_in[2];
  float* out = (float*)d_out;

  __hip_bfloat16* Kc = (__hip_bfloat16*)d_ws;       // 4 MiB
  __hip_bfloat16* Vt = Kc + ELEMS;                   // 4 MiB

  // fused prepass: blocks [0,1024) K relayout, [1024,1152) V transpose
  prep_kv_kernel<<<dim3(1152), 256, 0, stream>>>(K, V, Kc, Vt);
  // attention: 512 blocks = 8 XCD x 2 heads x 32 q-tiles (64 rows each)
  attn_kernel<<<dim3(512), 256, 0, stream>>>(Q, Kc, Vt, out);
}